// Round 15
// baseline (3910.084 us; speedup 1.0000x reference)
//
#include <hip/hip_runtime.h>
#include <hip/hip_bf16.h>

#define B_ 64
#define T_ 512
#define D_ 1024
#define H_ 1024

typedef __bf16 bf16x8 __attribute__((ext_vector_type(8)));
typedef float f32x4 __attribute__((ext_vector_type(4)));

static __device__ __forceinline__ unsigned short f2bf(float f) {
  union { float f; unsigned u; } v; v.f = f;
  unsigned u = v.u;
  unsigned r = (u + 0x7fffu + ((u >> 16) & 1u)) >> 16;
  return (unsigned short)r;
}

// ---------------------------------------------------------------------------
// xi = x @ Wi^T + bi -> out[B,T,H]  (validated rounds 2/5/6/7/8/9/10/12/14)
// ---------------------------------------------------------------------------
__global__ __launch_bounds__(256) void xi_gemm(const float* __restrict__ x,
                                               const float* __restrict__ Wi,
                                               const float* __restrict__ bi,
                                               float* __restrict__ out) {
  __shared__ __align__(16) unsigned short As[128][40];
  __shared__ __align__(16) unsigned short Ws[128][40];
  const int tid = threadIdx.x;
  const int wave = tid >> 6;
  const int lane = tid & 63;
  const int wm = wave >> 1, wn = wave & 1;
  const int lr = lane & 15, lk = lane >> 4;
  const long row0 = (long)blockIdx.x * 128;
  const int col0 = (int)blockIdx.y * 128;

  f32x4 acc[4][4];
#pragma unroll
  for (int m = 0; m < 4; ++m)
#pragma unroll
    for (int n = 0; n < 4; ++n)
      acc[m][n] = (f32x4){0.f, 0.f, 0.f, 0.f};

  for (int kt = 0; kt < 32; ++kt) {
    __syncthreads();
#pragma unroll
    for (int it = 0; it < 4; ++it) {
      int i = tid + it * 256;
      int row = i >> 3, c = i & 7;
      float4 va = *reinterpret_cast<const float4*>(
          &x[(row0 + row) * 1024 + kt * 32 + c * 4]);
      ushort4 ba = {f2bf(va.x), f2bf(va.y), f2bf(va.z), f2bf(va.w)};
      *reinterpret_cast<ushort4*>(&As[row][c * 4]) = ba;
      float4 vw = *reinterpret_cast<const float4*>(
          &Wi[(long)(col0 + row) * 1024 + kt * 32 + c * 4]);
      ushort4 bw = {f2bf(vw.x), f2bf(vw.y), f2bf(vw.z), f2bf(vw.w)};
      *reinterpret_cast<ushort4*>(&Ws[row][c * 4]) = bw;
    }
    __syncthreads();
    bf16x8 af[4], wf[4];
#pragma unroll
    for (int m = 0; m < 4; ++m)
      af[m] = *reinterpret_cast<const bf16x8*>(&As[wm * 64 + m * 16 + lr][lk * 8]);
#pragma unroll
    for (int n = 0; n < 4; ++n)
      wf[n] = *reinterpret_cast<const bf16x8*>(&Ws[wn * 64 + n * 16 + lr][lk * 8]);
#pragma unroll
    for (int m = 0; m < 4; ++m)
#pragma unroll
      for (int n = 0; n < 4; ++n)
        acc[m][n] = __builtin_amdgcn_mfma_f32_16x16x32_bf16(af[m], wf[n], acc[m][n], 0, 0, 0);
  }
#pragma unroll
  for (int m = 0; m < 4; ++m) {
#pragma unroll
    for (int n = 0; n < 4; ++n) {
#pragma unroll
      for (int r = 0; r < 4; ++r) {
        long row = row0 + wm * 64 + m * 16 + lk * 4 + r;
        int col = col0 + wn * 64 + n * 16 + lr;
        out[row * 1024 + col] = acc[m][n][r] + bi[col];
      }
    }
  }
}

// ---------------------------------------------------------------------------
// Persistent recurrence v10: r12 protocol (replay-proven: agent-atomic flags
// at LLC + per-step acquire fence + cached h in own XCD's L2), but with
// HALF the barrier participants: 128 blocks x 128 thr (2 waves), each block
// owns 64 j-cols, Wh slice [64][1028] bf16 = 131.6 KB dynamic LDS (stride
// 1028 also cuts B-frag bank conflicts 8-way -> 4-way). 16 flags/XCD.
// Each wave executes exactly the r12 per-step compute (2 col-tiles).
// Step: __syncthreads (drain both waves) -> tid0 agent-atomic flag=t ->
//       xi prefetch -> per-wave poll of own XCD's 16 flags -> per-wave
//       fence(acquire,"agent") -> cached h loads -> MFMA -> tanh -> stores.
// BAD placement -> FALLBACK: r8-semantics over 256 virtual blocks
// (bid*2+wave), per-block flag, 128-flag poll. All spins capped.
// ws: ctrs 256B @0 | flagsF 16KB @4096 | flagsB 16KB @20480 |
//     hsF 512KB @36864 ([xcd][2][16][1024] ushort) | hsB 256KB @561152.
// ---------------------------------------------------------------------------
__global__ __launch_bounds__(128) void rnn_xcd(const float* __restrict__ Wh,
                                               const float* __restrict__ bh,
                                               float* __restrict__ out,
                                               unsigned* __restrict__ ctrs,
                                               unsigned* __restrict__ flagsF,
                                               unsigned* __restrict__ flagsB,
                                               unsigned short* __restrict__ hsF,
                                               unsigned short* __restrict__ hsB) {
  extern __shared__ __align__(16) unsigned short Whs[];
  __shared__ unsigned meta[4];
  const int tid = threadIdx.x;
  const int wave = tid >> 6, lane = tid & 63;
  const int lr = lane & 15, lk = lane >> 4;

  // ---- phase 0: registration & placement validation (r10/r12-proven) ----
  if (tid == 0) {
    unsigned xcc = __builtin_amdgcn_s_getreg((31u << 11) | 20u) & 15u;
    unsigned slot = __hip_atomic_fetch_add(&ctrs[xcc], 1u, __ATOMIC_RELAXED,
                                           __HIP_MEMORY_SCOPE_AGENT);
    __hip_atomic_fetch_add(&ctrs[16], 1u, __ATOMIC_RELEASE,
                           __HIP_MEMORY_SCOPE_AGENT);
    unsigned spin = 0;
    while (__hip_atomic_load(&ctrs[16], __ATOMIC_ACQUIRE,
                             __HIP_MEMORY_SCOPE_AGENT) < 128u) {
      __builtin_amdgcn_s_sleep(1);
      if (++spin > 2000000u) break;
    }
    unsigned ok = 1;
    for (int i = 0; i < 8; ++i)
      if (__hip_atomic_load(&ctrs[i], __ATOMIC_RELAXED,
                            __HIP_MEMORY_SCOPE_AGENT) != 16u) ok = 0;
    for (int i = 8; i < 16; ++i)
      if (__hip_atomic_load(&ctrs[i], __ATOMIC_RELAXED,
                            __HIP_MEMORY_SCOPE_AGENT) != 0u) ok = 0;
    meta[0] = xcc; meta[1] = slot; meta[2] = ok;
  }
  __syncthreads();
  const unsigned xcc = meta[0], slot = meta[1], okv = meta[2];

  if (okv) {
    // ==================== FAST PATH (XCD-local data, LLC flags) ============
    const int j0 = (int)slot * 64;
    // stage Wh rows j0..j0+63 -> LDS [64][1028] bf16 (once)
#pragma unroll 8
    for (int it = 0; it < 128; ++it) {
      int i = tid + it * 128;
      int row = i >> 8, c = i & 255;
      float4 v = *reinterpret_cast<const float4*>(&Wh[(long)(j0 + row) * 1024 + c * 4]);
      ushort4 b4 = {f2bf(v.x), f2bf(v.y), f2bf(v.z), f2bf(v.w)};
      *reinterpret_cast<ushort4*>(&Whs[row * 1028 + c * 4]) = b4;
    }
    __syncthreads();

    const int wcol = wave * 32;
    const int jc0 = j0 + wcol + lr;
    const int jc1 = jc0 + 16;
    const float bhv0 = bh[jc0], bhv1 = bh[jc1];
    const unsigned short* wb0 = &Whs[(wcol + lr) * 1028 + lk * 8];
    const unsigned short* wb1 = &Whs[(wcol + 16 + lr) * 1028 + lk * 8];
    unsigned* hw = reinterpret_cast<unsigned*>(hsF);
    const unsigned fslot = (xcc * 16u + slot) << 4;

    for (int t = 0; t < T_; ++t) {
      float xr0[4], xr1[4];
      if (t > 0) {
        __syncthreads();  // both waves' h+out stores drained (vmcnt pre-bar)
        if (tid == 0)
          __hip_atomic_store(&flagsF[fslot], (unsigned)t,
                             __ATOMIC_RELAXED, __HIP_MEMORY_SCOPE_AGENT);
        // xi prefetch — HBM latency hides under the LLC poll (r12-proven)
        if (lk < 2) {
#pragma unroll
          for (int r = 0; r < 4; ++r) {
            size_t oi = ((size_t)(xcc * 8 + lk * 4 + r) * T_ + t) * H_;
            xr0[r] = out[oi + jc0];
            xr1[r] = out[oi + jc1];
          }
        }
        // per-wave poll of own XCD's 16 flags
        unsigned spin = 0;
        for (;;) {
          unsigned v = (unsigned)t;
          if (lane < 16)
            v = __hip_atomic_load(&flagsF[(xcc * 16u + (unsigned)lane) << 4],
                                  __ATOMIC_RELAXED, __HIP_MEMORY_SCOPE_AGENT);
          if (__all((int)(v >= (unsigned)t))) break;
          if (spin >= 8) __builtin_amdgcn_s_sleep(1);
          if (++spin > 50000u) break;  // fail loud, never wedge
        }
        __builtin_amdgcn_fence(__ATOMIC_ACQUIRE, "agent");  // per-wave inv
      } else {
        if (lk < 2) {
#pragma unroll
          for (int r = 0; r < 4; ++r) {
            size_t oi = ((size_t)(xcc * 8 + lk * 4 + r) * T_ + t) * H_;
            xr0[r] = out[oi + jc0];
            xr1[r] = out[oi + jc1];
          }
        }
      }

      f32x4 a00 = {0,0,0,0}, a01 = {0,0,0,0}, a10 = {0,0,0,0}, a11 = {0,0,0,0};
      if (t > 0) {
        const unsigned short* hp = hsF + (size_t)xcc * 32768 +
                                   (size_t)((t - 1) & 1) * 16384 +
                                   (size_t)lr * 1024 + lk * 8;
#pragma unroll 4
        for (int ks = 0; ks < 16; ++ks) {
          bf16x8 ah0 = *reinterpret_cast<const bf16x8*>(hp + ks * 32);
          bf16x8 ah1 = *reinterpret_cast<const bf16x8*>(hp + (ks + 16) * 32);
          bf16x8 w00 = *reinterpret_cast<const bf16x8*>(wb0 + ks * 32);
          bf16x8 w01 = *reinterpret_cast<const bf16x8*>(wb0 + (ks + 16) * 32);
          bf16x8 w10 = *reinterpret_cast<const bf16x8*>(wb1 + ks * 32);
          bf16x8 w11 = *reinterpret_cast<const bf16x8*>(wb1 + (ks + 16) * 32);
          a00 = __builtin_amdgcn_mfma_f32_16x16x32_bf16(ah0, w00, a00, 0, 0, 0);
          a01 = __builtin_amdgcn_mfma_f32_16x16x32_bf16(ah1, w01, a01, 0, 0, 0);
          a10 = __builtin_amdgcn_mfma_f32_16x16x32_bf16(ah0, w10, a10, 0, 0, 0);
          a11 = __builtin_amdgcn_mfma_f32_16x16x32_bf16(ah1, w11, a11, 0, 0, 0);
        }
      }
      f32x4 acc0 = a00 + a01, acc1 = a10 + a11;

      // epilogue: D rows lk*4+r; real batches = rows 0..7 (lk<2); rows 8..15
      // of hsF are zero-pad (memset at launch), never written.
      const unsigned pw = (unsigned)(t & 1) * 8192u;
      if (lk < 2) {
#pragma unroll
        for (int r = 0; r < 4; ++r) {
          int row = lk * 4 + r;                  // 0..7
          size_t oi = ((size_t)(xcc * 8 + row) * T_ + t) * H_;
          float h0 = tanhf(xr0[r] + acc0[r] + bhv0);
          float h1 = tanhf(xr1[r] + acc1[r] + bhv1);
          out[oi + jc0] = h0;
          out[oi + jc1] = h1;
          unsigned u0 = f2bf(h0), u1 = f2bf(h1);
          unsigned o0 = (unsigned)__shfl_xor((int)u0, 1, 64);
          unsigned o1 = (unsigned)__shfl_xor((int)u1, 1, 64);
          if ((lr & 1) == 0) {  // plain cached stores -> own XCD's L2
            unsigned base = xcc * 16384u + pw + (unsigned)row * 512u;
            hw[base + ((unsigned)jc0 >> 1)] = u0 | (o0 << 16);
            hw[base + ((unsigned)jc1 >> 1)] = u1 | (o1 << 16);
          }
        }
      }
    }
  } else {
    // ========= FALLBACK (LLC-synced, r8 semantics over virtual blocks) =====
    const int vbid = (int)blockIdx.x * 2 + wave;   // 0..255
    const int jg = vbid & 63, bg = vbid >> 6;
    const int j0f = jg * 16, brow = bg * 16;
    // per-wave staging of this wave's 16 Wh rows into its LDS segment
#pragma unroll 8
    for (int it = 0; it < 64; ++it) {
      int i = lane + it * 64;
      int row = i >> 8, c = i & 255;
      float4 v = *reinterpret_cast<const float4*>(&Wh[(long)(j0f + row) * 1024 + c * 4]);
      ushort4 b4 = {f2bf(v.x), f2bf(v.y), f2bf(v.z), f2bf(v.w)};
      *reinterpret_cast<ushort4*>(&Whs[(wave * 16 + row) * 1028 + c * 4]) = b4;
    }
    __syncthreads();
    const int jcol = j0f + lr;
    const float bhv = bh[jcol];
    const unsigned short* wbl = &Whs[(wave * 16 + lr) * 1028 + lk * 8];
    unsigned* hw = reinterpret_cast<unsigned*>(hsB);
    const int jp = jcol >> 1;

    for (int t = 0; t < T_; ++t) {
      if (t > 0) {
        __syncthreads();   // both waves' stores drained
        if (tid == 0)
          __hip_atomic_store(&flagsB[(unsigned)blockIdx.x << 4], (unsigned)t,
                             __ATOMIC_RELAXED, __HIP_MEMORY_SCOPE_AGENT);
        unsigned spin = 0;
        for (;;) {
          unsigned va = __hip_atomic_load(&flagsB[(unsigned)lane << 4],
                                 __ATOMIC_RELAXED, __HIP_MEMORY_SCOPE_AGENT);
          unsigned vb = __hip_atomic_load(&flagsB[((unsigned)lane + 64u) << 4],
                                 __ATOMIC_RELAXED, __HIP_MEMORY_SCOPE_AGENT);
          int ok = (va >= (unsigned)t) && (vb >= (unsigned)t);
          if (__all(ok)) break;
          __builtin_amdgcn_s_sleep(2);
          if (++spin > 50000u) break;
        }
        __builtin_amdgcn_fence(__ATOMIC_ACQUIRE, "agent");  // per-wave
      }

      f32x4 a0 = {0,0,0,0}, a1 = {0,0,0,0};
      if (t > 0) {
        const unsigned short* hbl = hsB + (size_t)((t - 1) & 1) * 65536 +
                                    (size_t)(brow + lr) * 1024 + lk * 8;
#pragma unroll 4
        for (int ks = 0; ks < 16; ++ks) {
          bf16x8 ah0 = *reinterpret_cast<const bf16x8*>(hbl + ks * 32);
          bf16x8 ah1 = *reinterpret_cast<const bf16x8*>(hbl + (ks + 16) * 32);
          bf16x8 wf0 = *reinterpret_cast<const bf16x8*>(wbl + ks * 32);
          bf16x8 wf1 = *reinterpret_cast<const bf16x8*>(wbl + (ks + 16) * 32);
          a0 = __builtin_amdgcn_mfma_f32_16x16x32_bf16(ah0, wf0, a0, 0, 0, 0);
          a1 = __builtin_amdgcn_mfma_f32_16x16x32_bf16(ah1, wf1, a1, 0, 0, 0);
        }
      }
      f32x4 acc = a0 + a1;

      const unsigned pw = (unsigned)(t & 1) * 32768u;
#pragma unroll
      for (int r = 0; r < 4; ++r) {
        int b = brow + lk * 4 + r;
        size_t oi = ((size_t)b * T_ + t) * H_ + jcol;
        float z = out[oi] + acc[r] + bhv;
        float h = tanhf(z);
        out[oi] = h;
        unsigned hi_u = f2bf(h);
        unsigned o_hi = (unsigned)__shfl_xor((int)hi_u, 1, 64);
        if ((lr & 1) == 0) {
          __hip_atomic_store(&hw[pw + (unsigned)b * 512u + (unsigned)jp],
                             hi_u | (o_hi << 16),
                             __ATOMIC_RELAXED, __HIP_MEMORY_SCOPE_AGENT);
        }
      }
    }
  }
}

// ---------------------------------------------------------------------------
// Last-resort fallback (round-2 validated): per-step kernel chain.
// ---------------------------------------------------------------------------
__global__ __launch_bounds__(256) void rnn_step(const float* __restrict__ Wh,
                                                const float* __restrict__ bh,
                                                float* __restrict__ out,
                                                int t) {
  const int bg = blockIdx.x & 3;
  const int jg = blockIdx.x >> 2;
  const int b = bg * 16 + (threadIdx.x >> 4);
  const int j = jg * 16 + (threadIdx.x & 15);
  float a0 = 0.f, a1 = 0.f, a2 = 0.f, a3 = 0.f;
  if (t > 0) {
    const float4* __restrict__ wr = reinterpret_cast<const float4*>(&Wh[(long)j * H_]);
    const float4* __restrict__ hr = reinterpret_cast<const float4*>(
        &out[((long)b * T_ + (t - 1)) * H_]);
#pragma unroll 8
    for (int kc = 0; kc < 256; ++kc) {
      float4 w = wr[kc];
      float4 h = hr[kc];
      a0 = fmaf(w.x, h.x, a0);
      a1 = fmaf(w.y, h.y, a1);
      a2 = fmaf(w.z, h.z, a2);
      a3 = fmaf(w.w, h.w, a3);
    }
  }
  const long oi = ((long)b * T_ + t) * H_ + j;
  float z = out[oi] + ((a0 + a1) + (a2 + a3)) + bh[j];
  out[oi] = tanhf(z);
}

extern "C" void kernel_launch(void* const* d_in, const int* in_sizes, int n_in,
                              void* d_out, int out_size, void* d_ws, size_t ws_size,
                              hipStream_t stream) {
  const float* x  = (const float*)d_in[0];
  const float* Wi = (const float*)d_in[1];
  const float* bi = (const float*)d_in[2];
  const float* Wh = (const float*)d_in[3];
  const float* bh = (const float*)d_in[4];
  float* out = (float*)d_out;

  const size_t CTRS_OFF  = 0;        // 256 B
  const size_t FLAGF_OFF = 4096;     // 16 KB (128 slots used)
  const size_t FLAGB_OFF = 20480;    // 16 KB (128 slots used)
  const size_t HSF_OFF   = 36864;    // 512 KB ([8][2][16][1024] ushort)
  const size_t HSB_OFF   = 561152;   // 256 KB ([2][64][1024] ushort)
  const size_t NEED      = HSB_OFF + 262144;

  hipLaunchKernelGGL(xi_gemm, dim3(256, 8), dim3(256), 0, stream, x, Wi, bi, out);

  bool launched = false;
  if (ws_size >= NEED) {
    unsigned* ctrs = (unsigned*)((char*)d_ws + CTRS_OFF);
    unsigned* flagsF = (unsigned*)((char*)d_ws + FLAGF_OFF);
    unsigned* flagsB = (unsigned*)((char*)d_ws + FLAGB_OFF);
    unsigned short* hsF = (unsigned short*)((char*)d_ws + HSF_OFF);
    unsigned short* hsB = (unsigned short*)((char*)d_ws + HSB_OFF);
    // zero ctrs + both flag arrays + hsF (pad rows must be 0 every call) —
    // exactly the r12 (replay-proven) reset scheme.
    hipMemsetAsync(d_ws, 0, HSF_OFF + 524288, stream);

    const float* Wh_ = Wh; const float* bh_ = bh; float* out_ = out;
    void* args[] = {(void*)&Wh_, (void*)&bh_, (void*)&out_,
                    (void*)&ctrs, (void*)&flagsF, (void*)&flagsB,
                    (void*)&hsF, (void*)&hsB};
    const int lds = 64 * 1028 * 2;  // 131584 B dynamic LDS
    hipError_t e = hipFuncSetAttribute(
        reinterpret_cast<const void*>(rnn_xcd),
        hipFuncAttributeMaxDynamicSharedMemorySize, lds);
    if (e == hipSuccess)
      e = hipLaunchCooperativeKernel((void*)rnn_xcd, dim3(128), dim3(128),
                                     args, lds, stream);
    launched = (e == hipSuccess);
  }
  if (!launched) {
    for (int t = 0; t < T_; ++t)
      hipLaunchKernelGGL(rnn_step, dim3(256), dim3(256), 0, stream, Wh, bh, out, t);
  }
}

// Round 17
// 3441.168 us; speedup vs baseline: 1.1363x; 1.1363x over previous
//
#include <hip/hip_runtime.h>
#include <hip/hip_bf16.h>

#define B_ 64
#define T_ 512
#define D_ 1024
#define H_ 1024

typedef __bf16 bf16x8 __attribute__((ext_vector_type(8)));
typedef float f32x4 __attribute__((ext_vector_type(4)));

static __device__ __forceinline__ unsigned short f2bf(float f) {
  union { float f; unsigned u; } v; v.f = f;
  unsigned u = v.u;
  unsigned r = (u + 0x7fffu + ((u >> 16) & 1u)) >> 16;
  return (unsigned short)r;
}

// ---------------------------------------------------------------------------
// xi = x @ Wi^T + bi -> out[B,T,H]  (validated rounds 2/5/6/7/8/9/10/12/14/15)
// ---------------------------------------------------------------------------
__global__ __launch_bounds__(256) void xi_gemm(const float* __restrict__ x,
                                               const float* __restrict__ Wi,
                                               const float* __restrict__ bi,
                                               float* __restrict__ out) {
  __shared__ __align__(16) unsigned short As[128][40];
  __shared__ __align__(16) unsigned short Ws[128][40];
  const int tid = threadIdx.x;
  const int wave = tid >> 6;
  const int lane = tid & 63;
  const int wm = wave >> 1, wn = wave & 1;
  const int lr = lane & 15, lk = lane >> 4;
  const long row0 = (long)blockIdx.x * 128;
  const int col0 = (int)blockIdx.y * 128;

  f32x4 acc[4][4];
#pragma unroll
  for (int m = 0; m < 4; ++m)
#pragma unroll
    for (int n = 0; n < 4; ++n)
      acc[m][n] = (f32x4){0.f, 0.f, 0.f, 0.f};

  for (int kt = 0; kt < 32; ++kt) {
    __syncthreads();
#pragma unroll
    for (int it = 0; it < 4; ++it) {
      int i = tid + it * 256;
      int row = i >> 3, c = i & 7;
      float4 va = *reinterpret_cast<const float4*>(
          &x[(row0 + row) * 1024 + kt * 32 + c * 4]);
      ushort4 ba = {f2bf(va.x), f2bf(va.y), f2bf(va.z), f2bf(va.w)};
      *reinterpret_cast<ushort4*>(&As[row][c * 4]) = ba;
      float4 vw = *reinterpret_cast<const float4*>(
          &Wi[(long)(col0 + row) * 1024 + kt * 32 + c * 4]);
      ushort4 bw = {f2bf(vw.x), f2bf(vw.y), f2bf(vw.z), f2bf(vw.w)};
      *reinterpret_cast<ushort4*>(&Ws[row][c * 4]) = bw;
    }
    __syncthreads();
    bf16x8 af[4], wf[4];
#pragma unroll
    for (int m = 0; m < 4; ++m)
      af[m] = *reinterpret_cast<const bf16x8*>(&As[wm * 64 + m * 16 + lr][lk * 8]);
#pragma unroll
    for (int n = 0; n < 4; ++n)
      wf[n] = *reinterpret_cast<const bf16x8*>(&Ws[wn * 64 + n * 16 + lr][lk * 8]);
#pragma unroll
    for (int m = 0; m < 4; ++m)
#pragma unroll
      for (int n = 0; n < 4; ++n)
        acc[m][n] = __builtin_amdgcn_mfma_f32_16x16x32_bf16(af[m], wf[n], acc[m][n], 0, 0, 0);
  }
#pragma unroll
  for (int m = 0; m < 4; ++m) {
#pragma unroll
    for (int n = 0; n < 4; ++n) {
#pragma unroll
      for (int r = 0; r < 4; ++r) {
        long row = row0 + wm * 64 + m * 16 + lk * 4 + r;
        int col = col0 + wn * 64 + n * 16 + lr;
        out[row * 1024 + col] = acc[m][n][r] + bi[col];
      }
    }
  }
}

// ---------------------------------------------------------------------------
// Persistent recurrence — r12 protocol RESTORED VERBATIM (replay-proven:
// agent-atomic flags at LLC + per-step acquire fence + cached h in own XCD's
// L2). Deviations tried and rejected: L2-local flags (r11/r13: replay-broken),
// participant halving (r15: worse), xi reg double-buffer (r14: neutral),
// fence removal (r16: broken even on first run — sc0 loads do NOT observe
// peer CUs' plain stores without the acquire fence). Every element here is
// load-bearing.
// FAST step protocol:
//   s_waitcnt vmcnt(0)            h+out stores retired (xi NOT outstanding)
//   flag: agent atomic store t    -> LLC
//   xi prefetch (cached)          HBM latency hides under the LLC poll
//   poll: agent atomic loads of own XCD's 32 flags until all >= t
//   fence(acquire,"agent")        inv L1/L2-clean; dirty h lines survive;
//                                 xi already drained into regs by the poll
//   h cached loads + MFMA (Wh from LDS) -> tanh -> plain stores (h -> L2)
// BAD placement -> FALLBACK: round-8-semantics LLC path (validated).
// ws: ctrs 256B @0 | flagsF 16KB @4096 | flagsB 16KB @20480 |
//     hsF 512KB @36864 ([xcd][2][16][1024] ushort) | hsB 256KB @561152.
// ---------------------------------------------------------------------------
__global__ __launch_bounds__(64) void rnn_xcd(const float* __restrict__ Wh,
                                              const float* __restrict__ bh,
                                              float* __restrict__ out,
                                              unsigned* __restrict__ ctrs,
                                              unsigned* __restrict__ flagsF,
                                              unsigned* __restrict__ flagsB,
                                              unsigned short* __restrict__ hsF,
                                              unsigned short* __restrict__ hsB) {
  extern __shared__ __align__(16) unsigned short Whs[];
  const int lane = threadIdx.x;
  const int lr = lane & 15, lk = lane >> 4;

  // ---- phase 0: registration & placement validation (round-10 validated) ----
  unsigned xcc = 0, slot = 0, okv = 0;
  if (lane == 0) {
    xcc = __builtin_amdgcn_s_getreg((31u << 11) | 20u) & 15u;  // HW_REG_XCC_ID
    slot = __hip_atomic_fetch_add(&ctrs[xcc], 1u, __ATOMIC_RELAXED,
                                  __HIP_MEMORY_SCOPE_AGENT);
    __hip_atomic_fetch_add(&ctrs[16], 1u, __ATOMIC_RELEASE,
                           __HIP_MEMORY_SCOPE_AGENT);
    unsigned spin = 0;
    while (__hip_atomic_load(&ctrs[16], __ATOMIC_ACQUIRE,
                             __HIP_MEMORY_SCOPE_AGENT) < 256u) {
      __builtin_amdgcn_s_sleep(1);
      if (++spin > 2000000u) break;
    }
    unsigned ok = 1;
    for (int i = 0; i < 8; ++i)
      if (__hip_atomic_load(&ctrs[i], __ATOMIC_RELAXED,
                            __HIP_MEMORY_SCOPE_AGENT) != 32u) ok = 0;
    for (int i = 8; i < 16; ++i)
      if (__hip_atomic_load(&ctrs[i], __ATOMIC_RELAXED,
                            __HIP_MEMORY_SCOPE_AGENT) != 0u) ok = 0;
    okv = ok;
  }
  xcc  = (unsigned)__shfl((int)xcc, 0, 64);
  slot = (unsigned)__shfl((int)slot, 0, 64);
  okv  = (unsigned)__shfl((int)okv, 0, 64);

  if (okv) {
    // ==================== FAST PATH (XCD-local data, LLC flags) ============
    const int j0 = (int)slot * 32;
#pragma unroll 8
    for (int it = 0; it < 128; ++it) {
      int i = lane + it * 64;
      int row = i >> 8, c = i & 255;
      float4 v = *reinterpret_cast<const float4*>(&Wh[(long)(j0 + row) * 1024 + c * 4]);
      ushort4 b4 = {f2bf(v.x), f2bf(v.y), f2bf(v.z), f2bf(v.w)};
      *reinterpret_cast<ushort4*>(&Whs[row * 1032 + c * 4]) = b4;
    }
    __syncthreads();

    const int jc0 = j0 + lr;
    const int jc1 = j0 + 16 + lr;
    const float bhv0 = bh[jc0], bhv1 = bh[jc1];
    const unsigned short* wb0 = &Whs[lr * 1032 + lk * 8];
    const unsigned short* wb1 = &Whs[(16 + lr) * 1032 + lk * 8];
    unsigned* hw = reinterpret_cast<unsigned*>(hsF);
    const unsigned fslot = (xcc * 32u + slot) << 4;

    for (int t = 0; t < T_; ++t) {
      float xr0[4], xr1[4];
      if (t > 0) {
        // drain = h+out stores only (xi deliberately NOT outstanding here)
        asm volatile("s_waitcnt vmcnt(0)" ::: "memory");
        if (lane == 0)
          __hip_atomic_store(&flagsF[fslot], (unsigned)t,
                             __ATOMIC_RELAXED, __HIP_MEMORY_SCOPE_AGENT);
        // xi prefetch issued now — HBM latency hides under the LLC poll;
        // each poll iteration's atomic load drains vmcnt -> xi lands in regs
        // before the fence (registers unaffected by cache-inv).
        if (lk < 2) {
#pragma unroll
          for (int r = 0; r < 4; ++r) {
            size_t oi = ((size_t)(xcc * 8 + lk * 4 + r) * T_ + t) * H_;
            xr0[r] = out[oi + jc0];
            xr1[r] = out[oi + jc1];
          }
        }
        unsigned spin = 0;
        for (;;) {
          unsigned v = (unsigned)t;
          if (lane < 32)
            v = __hip_atomic_load(&flagsF[(xcc * 32u + (unsigned)lane) << 4],
                                  __ATOMIC_RELAXED, __HIP_MEMORY_SCOPE_AGENT);
          if (__all((int)(v >= (unsigned)t))) break;
          if (spin >= 2) __builtin_amdgcn_s_sleep(1);
          if (++spin > 50000u) break;  // fail loud, never wedge
        }
        __builtin_amdgcn_fence(__ATOMIC_ACQUIRE, "agent");  // inv L1/L2-clean
      } else {
        if (lk < 2) {
#pragma unroll
          for (int r = 0; r < 4; ++r) {
            size_t oi = ((size_t)(xcc * 8 + lk * 4 + r) * T_ + t) * H_;
            xr0[r] = out[oi + jc0];
            xr1[r] = out[oi + jc1];
          }
        }
      }

      f32x4 a00 = {0,0,0,0}, a01 = {0,0,0,0}, a10 = {0,0,0,0}, a11 = {0,0,0,0};
      if (t > 0) {
        const unsigned short* hp = hsF + (size_t)xcc * 32768 +
                                   (size_t)((t - 1) & 1) * 16384 +
                                   (size_t)lr * 1024 + lk * 8;
#pragma unroll 4
        for (int ks = 0; ks < 16; ++ks) {
          bf16x8 ah0 = *reinterpret_cast<const bf16x8*>(hp + ks * 32);
          bf16x8 ah1 = *reinterpret_cast<const bf16x8*>(hp + (ks + 16) * 32);
          bf16x8 w00 = *reinterpret_cast<const bf16x8*>(wb0 + ks * 32);
          bf16x8 w01 = *reinterpret_cast<const bf16x8*>(wb0 + (ks + 16) * 32);
          bf16x8 w10 = *reinterpret_cast<const bf16x8*>(wb1 + ks * 32);
          bf16x8 w11 = *reinterpret_cast<const bf16x8*>(wb1 + (ks + 16) * 32);
          a00 = __builtin_amdgcn_mfma_f32_16x16x32_bf16(ah0, w00, a00, 0, 0, 0);
          a01 = __builtin_amdgcn_mfma_f32_16x16x32_bf16(ah1, w01, a01, 0, 0, 0);
          a10 = __builtin_amdgcn_mfma_f32_16x16x32_bf16(ah0, w10, a10, 0, 0, 0);
          a11 = __builtin_amdgcn_mfma_f32_16x16x32_bf16(ah1, w11, a11, 0, 0, 0);
        }
      }
      f32x4 acc0 = a00 + a01, acc1 = a10 + a11;

      // epilogue: D rows lk*4+r; real batches = rows 0..7 (lk<2); rows 8..15
      // of hsF are zero-pad (memset at launch), never written.
      const unsigned pw = (unsigned)(t & 1) * 8192u;
      if (lk < 2) {
#pragma unroll
        for (int r = 0; r < 4; ++r) {
          int row = lk * 4 + r;                  // 0..7
          size_t oi = ((size_t)(xcc * 8 + row) * T_ + t) * H_;
          float h0 = tanhf(xr0[r] + acc0[r] + bhv0);
          float h1 = tanhf(xr1[r] + acc1[r] + bhv1);
          out[oi + jc0] = h0;
          out[oi + jc1] = h1;
          unsigned u0 = f2bf(h0), u1 = f2bf(h1);
          unsigned o0 = (unsigned)__shfl_xor((int)u0, 1, 64);
          unsigned o1 = (unsigned)__shfl_xor((int)u1, 1, 64);
          if ((lr & 1) == 0) {  // plain cached stores -> own XCD's L2
            unsigned base = xcc * 16384u + pw + (unsigned)row * 512u;
            hw[base + ((unsigned)jc0 >> 1)] = u0 | (o0 << 16);
            hw[base + ((unsigned)jc1 >> 1)] = u1 | (o1 << 16);
          }
        }
      }
    }
  } else {
    // ============== FALLBACK (LLC-synced, round-8 semantics, validated) ====
    const int bid = (int)blockIdx.x;
    const int jg = bid & 63, bg = bid >> 6;
    const int j0 = jg * 16, brow = bg * 16;
#pragma unroll 8
    for (int it = 0; it < 64; ++it) {
      int i = lane + it * 64;
      int row = i >> 8, c = i & 255;
      float4 v = *reinterpret_cast<const float4*>(&Wh[(long)(j0 + row) * 1024 + c * 4]);
      ushort4 b4 = {f2bf(v.x), f2bf(v.y), f2bf(v.z), f2bf(v.w)};
      *reinterpret_cast<ushort4*>(&Whs[row * 1032 + c * 4]) = b4;
    }
    __syncthreads();
    const int jcol = j0 + lr;
    const float bhv = bh[jcol];
    const unsigned short* wbl = &Whs[lr * 1032 + lk * 8];
    unsigned* hw = reinterpret_cast<unsigned*>(hsB);
    const int jp = jcol >> 1;

    for (int t = 0; t < T_; ++t) {
      if (t > 0) {
        asm volatile("s_waitcnt vmcnt(0)" ::: "memory");
        if (lane == 0)
          __hip_atomic_store(&flagsB[(unsigned)bid << 4], (unsigned)t,
                             __ATOMIC_RELAXED, __HIP_MEMORY_SCOPE_AGENT);
        unsigned spin = 0;
        for (;;) {
          unsigned va = __hip_atomic_load(&flagsB[(unsigned)lane << 4],
                                 __ATOMIC_RELAXED, __HIP_MEMORY_SCOPE_AGENT);
          unsigned vb = __hip_atomic_load(&flagsB[((unsigned)lane + 64u) << 4],
                                 __ATOMIC_RELAXED, __HIP_MEMORY_SCOPE_AGENT);
          unsigned vc = __hip_atomic_load(&flagsB[((unsigned)lane + 128u) << 4],
                                 __ATOMIC_RELAXED, __HIP_MEMORY_SCOPE_AGENT);
          unsigned vd = __hip_atomic_load(&flagsB[((unsigned)lane + 192u) << 4],
                                 __ATOMIC_RELAXED, __HIP_MEMORY_SCOPE_AGENT);
          int ok = (va >= (unsigned)t) && (vb >= (unsigned)t) &&
                   (vc >= (unsigned)t) && (vd >= (unsigned)t);
          if (__all(ok)) break;
          __builtin_amdgcn_s_sleep(2);
          if (++spin > 50000u) break;
        }
        __builtin_amdgcn_fence(__ATOMIC_ACQUIRE, "agent");
      }

      f32x4 a0 = {0,0,0,0}, a1 = {0,0,0,0};
      if (t > 0) {
        const unsigned short* hbl = hsB + (size_t)((t - 1) & 1) * 65536 +
                                    (size_t)(brow + lr) * 1024 + lk * 8;
#pragma unroll 4
        for (int ks = 0; ks < 16; ++ks) {
          bf16x8 ah0 = *reinterpret_cast<const bf16x8*>(hbl + ks * 32);
          bf16x8 ah1 = *reinterpret_cast<const bf16x8*>(hbl + (ks + 16) * 32);
          bf16x8 wf0 = *reinterpret_cast<const bf16x8*>(wbl + ks * 32);
          bf16x8 wf1 = *reinterpret_cast<const bf16x8*>(wbl + (ks + 16) * 32);
          a0 = __builtin_amdgcn_mfma_f32_16x16x32_bf16(ah0, wf0, a0, 0, 0, 0);
          a1 = __builtin_amdgcn_mfma_f32_16x16x32_bf16(ah1, wf1, a1, 0, 0, 0);
        }
      }
      f32x4 acc = a0 + a1;

      const unsigned pw = (unsigned)(t & 1) * 32768u;
#pragma unroll
      for (int r = 0; r < 4; ++r) {
        int b = brow + lk * 4 + r;
        size_t oi = ((size_t)b * T_ + t) * H_ + jcol;
        float z = out[oi] + acc[r] + bhv;
        float h = tanhf(z);
        out[oi] = h;
        unsigned hi_u = f2bf(h);
        unsigned o_hi = (unsigned)__shfl_xor((int)hi_u, 1, 64);
        if ((lr & 1) == 0) {
          __hip_atomic_store(&hw[pw + (unsigned)b * 512u + (unsigned)jp],
                             hi_u | (o_hi << 16),
                             __ATOMIC_RELAXED, __HIP_MEMORY_SCOPE_AGENT);
        }
      }
    }
  }
}

// ---------------------------------------------------------------------------
// Last-resort fallback (round-2 validated): per-step kernel chain.
// ---------------------------------------------------------------------------
__global__ __launch_bounds__(256) void rnn_step(const float* __restrict__ Wh,
                                                const float* __restrict__ bh,
                                                float* __restrict__ out,
                                                int t) {
  const int bg = blockIdx.x & 3;
  const int jg = blockIdx.x >> 2;
  const int b = bg * 16 + (threadIdx.x >> 4);
  const int j = jg * 16 + (threadIdx.x & 15);
  float a0 = 0.f, a1 = 0.f, a2 = 0.f, a3 = 0.f;
  if (t > 0) {
    const float4* __restrict__ wr = reinterpret_cast<const float4*>(&Wh[(long)j * H_]);
    const float4* __restrict__ hr = reinterpret_cast<const float4*>(
        &out[((long)b * T_ + (t - 1)) * H_]);
#pragma unroll 8
    for (int kc = 0; kc < 256; ++kc) {
      float4 w = wr[kc];
      float4 h = hr[kc];
      a0 = fmaf(w.x, h.x, a0);
      a1 = fmaf(w.y, h.y, a1);
      a2 = fmaf(w.z, h.z, a2);
      a3 = fmaf(w.w, h.w, a3);
    }
  }
  const long oi = ((long)b * T_ + t) * H_ + j;
  float z = out[oi] + ((a0 + a1) + (a2 + a3)) + bh[j];
  out[oi] = tanhf(z);
}

extern "C" void kernel_launch(void* const* d_in, const int* in_sizes, int n_in,
                              void* d_out, int out_size, void* d_ws, size_t ws_size,
                              hipStream_t stream) {
  const float* x  = (const float*)d_in[0];
  const float* Wi = (const float*)d_in[1];
  const float* bi = (const float*)d_in[2];
  const float* Wh = (const float*)d_in[3];
  const float* bh = (const float*)d_in[4];
  float* out = (float*)d_out;

  const size_t CTRS_OFF  = 0;        // 256 B
  const size_t FLAGF_OFF = 4096;     // 16 KB
  const size_t FLAGB_OFF = 20480;    // 16 KB
  const size_t HSF_OFF   = 36864;    // 512 KB ([8][2][16][1024] ushort)
  const size_t HSB_OFF   = 561152;   // 256 KB ([2][64][1024] ushort)
  const size_t NEED      = HSB_OFF + 262144;

  hipLaunchKernelGGL(xi_gemm, dim3(256, 8), dim3(256), 0, stream, x, Wi, bi, out);

  bool launched = false;
  if (ws_size >= NEED) {
    unsigned* ctrs = (unsigned*)((char*)d_ws + CTRS_OFF);
    unsigned* flagsF = (unsigned*)((char*)d_ws + FLAGF_OFF);
    unsigned* flagsB = (unsigned*)((char*)d_ws + FLAGB_OFF);
    unsigned short* hsF = (unsigned short*)((char*)d_ws + HSF_OFF);
    unsigned short* hsB = (unsigned short*)((char*)d_ws + HSB_OFF);
    // zero ctrs + both flag arrays + hsF (pad rows must be 0 every call) —
    // the r12 (replay-proven) reset scheme.
    hipMemsetAsync(d_ws, 0, HSF_OFF + 524288, stream);

    const float* Wh_ = Wh; const float* bh_ = bh; float* out_ = out;
    void* args[] = {(void*)&Wh_, (void*)&bh_, (void*)&out_,
                    (void*)&ctrs, (void*)&flagsF, (void*)&flagsB,
                    (void*)&hsF, (void*)&hsB};
    const int lds = 32 * 1032 * 2;  // 66048 B dynamic LDS
    hipError_t e = hipFuncSetAttribute(
        reinterpret_cast<const void*>(rnn_xcd),
        hipFuncAttributeMaxDynamicSharedMemorySize, lds);
    if (e == hipSuccess)
      e = hipLaunchCooperativeKernel((void*)rnn_xcd, dim3(256), dim3(64),
                                     args, lds, stream);
    launched = (e == hipSuccess);
  }
  if (!launched) {
    for (int t = 0; t < T_; ++t)
      hipLaunchKernelGGL(rnn_step, dim3(256), dim3(256), 0, stream, Wh, bh, out, t);
  }
}